// Round 1
// baseline (681.453 us; speedup 1.0000x reference)
//
#include <hip/hip_runtime.h>

#define T_STEPS 1024
// H = F = 6, 4H = 24 gate rows, PyTorch order: i[0:6) f[6:12) g[12:18) o[18:24)

__device__ __forceinline__ float vexp2(float x) { return __builtin_amdgcn_exp2f(x); }
__device__ __forceinline__ float vrcp(float x)  { return __builtin_amdgcn_rcpf(x); }
// sigmoid(x) = 1/(1+exp(-x)) = rcp(1 + 2^(-x*log2e))
__device__ __forceinline__ float sigm(float x) {
    return vrcp(1.0f + vexp2(x * -1.44269504088896340736f));
}
// tanh(x) = 2*sigmoid(2x) - 1
__device__ __forceinline__ float tanh_f(float x) {
    return fmaf(2.0f, sigm(2.0f * x), -1.0f);
}

// One LSTM step for this lane's two gate rows.
// p0 lanes (l even): rows = (i_j, g_j), own c_j/h_j.  p1 lanes: rows = (f_j, o_j).
__device__ __forceinline__ float lstm_step(
    const float in[6], float hs[6], float& c,
    const float wihA[6], const float whhA[6], float bA,
    const float wihB[6], const float whhB[6], float bB,
    int p0, int gbase)
{
    float sA = bA, tA = 0.0f, sB = bB, tB = 0.0f;
#pragma unroll
    for (int k = 0; k < 6; ++k) {
        sA = fmaf(wihA[k], in[k], sA);
        tA = fmaf(whhA[k], hs[k], tA);
        sB = fmaf(wihB[k], in[k], sB);
        tB = fmaf(whhB[k], hs[k], tB);
    }
    float gA = sA + tA;   // i_j (p0) or f_j (p1)
    float gB = sB + tB;   // g_j (p0) or o_j (p1)

    float a0 = sigm(gA);                               // sigma(i) or sigma(f)
    float pre = p0 ? 2.0f * gB : gB;
    float sb = sigm(pre);
    float a1 = p0 ? fmaf(2.0f, sb, -1.0f) : sb;        // tanh(g) or sigma(o)

    float af = __shfl_xor(a0, 1, 64);                  // on p0: sigma(f) from partner
    float ao = __shfl_xor(a1, 1, 64);                  // on p0: sigma(o) from partner

    c = fmaf(af, c, a0 * a1);                          // valid on p0 lanes
    float hv = ao * tanh_f(c);                         // valid on p0 lanes

#pragma unroll
    for (int k = 0; k < 6; ++k)
        hs[k] = __shfl(hv, gbase + 2 * k, 64);         // broadcast from even lanes
    return hv;
}

__global__ __launch_bounds__(256) void lstm2_kernel(
    const float* __restrict__ x,
    const float* __restrict__ wih0, const float* __restrict__ whh0,
    const float* __restrict__ bih0, const float* __restrict__ bhh0,
    const float* __restrict__ wih1, const float* __restrict__ whh1,
    const float* __restrict__ bih1, const float* __restrict__ bhh1,
    float* __restrict__ out, int Btot)
{
    const int tid = threadIdx.x;
    const int grp = tid >> 4;          // 16 elements per 256-thread block
    const int l   = tid & 15;          // lane within element group
    const int b   = blockIdx.x * 16 + grp;
    if (b >= Btot) return;             // uniform per group; B%16==0 in practice

    const int p0 = ((l & 1) == 0) ? 1 : 0;
    int j = l >> 1; if (j > 5) j = 5;  // lanes 12..15 duplicate j=5 (results unused)
    const int rA = p0 ? j       : 6 + j;    // i_j or f_j
    const int rB = p0 ? 12 + j  : 18 + j;   // g_j or o_j

    // --- per-lane weights (L1-broadcast loads, done once) ---
    float wihA0[6], whhA0[6], wihB0[6], whhB0[6];
    float wihA1[6], whhA1[6], wihB1[6], whhB1[6];
#pragma unroll
    for (int k = 0; k < 6; ++k) {
        wihA0[k] = wih0[rA * 6 + k]; whhA0[k] = whh0[rA * 6 + k];
        wihB0[k] = wih0[rB * 6 + k]; whhB0[k] = whh0[rB * 6 + k];
        wihA1[k] = wih1[rA * 6 + k]; whhA1[k] = whh1[rA * 6 + k];
        wihB1[k] = wih1[rB * 6 + k]; whhB1[k] = whh1[rB * 6 + k];
    }
    const float bA0 = bih0[rA] + bhh0[rA];
    const float bB0 = bih0[rB] + bhh0[rB];
    const float bA1 = bih1[rA] + bhh1[rA];
    const float bB1 = bih1[rB] + bhh1[rB];

    const int wlane = tid & 63;
    const int gbase = wlane & ~15;     // group base lane within wave

    float h0s[6], h1s[6];
#pragma unroll
    for (int k = 0; k < 6; ++k) { h0s[k] = 0.0f; h1s[k] = 0.0f; }
    float c0 = 0.0f, c1 = 0.0f;

    const float* px  = x   + (size_t)b * (T_STEPS * 6);
    float*       pout = out + (size_t)b * (T_STEPS * 6);

    auto loadx = [&](int t, float v[6]) {
        const float2* p2 = reinterpret_cast<const float2*>(px + (size_t)t * 6);
        float2 a = p2[0], bq = p2[1], cq = p2[2];
        v[0] = a.x; v[1] = a.y; v[2] = bq.x; v[3] = bq.y; v[4] = cq.x; v[5] = cq.y;
    };

    float xn[6];
    {   // prologue: layer0 at t=0
        float xv[6];
        loadx(0, xv);
        loadx(1, xn);
        lstm_step(xv, h0s, c0, wihA0, whhA0, bA0, wihB0, whhB0, bB0, p0, gbase);
    }

    // body at t: layer1(t-1) [uses h0s=h0(t-1)] and layer0(t) are independent
    // chains -> scheduler interleaves them to hide trans/shuffle latency.
    for (int t = 1; t < T_STEPS; ++t) {
        float in1[6], xc[6];
#pragma unroll
        for (int k = 0; k < 6; ++k) { in1[k] = h0s[k]; xc[k] = xn[k]; }

        int tn = t + 1; if (tn > T_STEPS - 1) tn = T_STEPS - 1;
        loadx(tn, xn);                 // prefetch a full iteration ahead

        float hv1 = lstm_step(in1, h1s, c1, wihA1, whhA1, bA1,
                              wihB1, whhB1, bB1, p0, gbase);     // layer1(t-1)
        lstm_step(xc, h0s, c0, wihA0, whhA0, bA0,
                  wihB0, whhB0, bB0, p0, gbase);                 // layer0(t)

        if (p0 && l < 12)
            pout[(size_t)(t - 1) * 6 + j] = hv1;
    }

    {   // epilogue: layer1 at t = T-1
        float hv1 = lstm_step(h0s, h1s, c1, wihA1, whhA1, bA1,
                              wihB1, whhB1, bB1, p0, gbase);
        if (p0 && l < 12)
            pout[(size_t)(T_STEPS - 1) * 6 + j] = hv1;
    }
}

extern "C" void kernel_launch(void* const* d_in, const int* in_sizes, int n_in,
                              void* d_out, int out_size, void* d_ws, size_t ws_size,
                              hipStream_t stream)
{
    const float* x    = (const float*)d_in[0];
    const float* wih0 = (const float*)d_in[1];
    const float* whh0 = (const float*)d_in[2];
    const float* bih0 = (const float*)d_in[3];
    const float* bhh0 = (const float*)d_in[4];
    const float* wih1 = (const float*)d_in[5];
    const float* whh1 = (const float*)d_in[6];
    const float* bih1 = (const float*)d_in[7];
    const float* bhh1 = (const float*)d_in[8];
    float* out = (float*)d_out;

    const int Btot   = in_sizes[0] / (T_STEPS * 6);
    const int blocks = (Btot + 15) / 16;
    hipLaunchKernelGGL(lstm2_kernel, dim3(blocks), dim3(256), 0, stream,
                       x, wih0, whh0, bih0, bhh0, wih1, whh1, bih1, bhh1, out, Btot);
}